// Round 1
// baseline (117.826 us; speedup 1.0000x reference)
//
#include <hip/hip_runtime.h>
#include <cstdint>
#include <cstddef>

typedef __bf16 bf16x8 __attribute__((ext_vector_type(8)));
typedef float f32x4 __attribute__((ext_vector_type(4)));
typedef unsigned short u16;
typedef unsigned short u16x8 __attribute__((ext_vector_type(8)));

__device__ __forceinline__ u16 f2b(float f) {
    union { float f; uint32_t u; } v; v.f = f;
    uint32_t r = v.u + 0x7fffu + ((v.u >> 16) & 1u);
    return (u16)(r >> 16);
}
__device__ __forceinline__ float b2f(u16 h) {
    union { uint32_t u; float f; } v; v.u = ((uint32_t)h) << 16; return v.f;
}

#define NB 2
#define NSEQ 1024
#define DIMC 512
#define NHEAD 8
#define DHEAD 64

// ---------------- kernel 1: t = silu(time) @ Wt^T + bt  -> tbuf[B][1024]
__global__ __launch_bounds__(128) void time_cond_kernel(
    const float* __restrict__ timep, const float* __restrict__ Wt,
    const float* __restrict__ bt, float* __restrict__ tbuf)
{
    __shared__ float st[512];
    int bx = blockIdx.x;             // 16 blocks: b*8 + chunk
    int b = bx >> 3, ch = bx & 7;
    int tid = threadIdx.x;
    for (int k = tid; k < 512; k += 128) {
        float v = timep[b * 512 + k];
        st[k] = v / (1.f + __expf(-v));
    }
    __syncthreads();
    int o = ch * 128 + tid;
    const float4* wrow = (const float4*)(Wt + (size_t)o * 512);
    float acc = bt[o];
    #pragma unroll 4
    for (int k4 = 0; k4 < 128; k4++) {
        float4 w = wrow[k4];
        acc += st[k4*4+0]*w.x + st[k4*4+1]*w.y + st[k4*4+2]*w.z + st[k4*4+3]*w.w;
    }
    tbuf[b * 1024 + o] = acc;
}

// ---------------- kernel 2: LayerNorm + (scale+1)*x + shift, * mask -> xn bf16
__global__ __launch_bounds__(64) void ln_cond_kernel(
    const float* __restrict__ x, const float* __restrict__ gamma,
    const float* __restrict__ tbuf, const float* __restrict__ seq_mask,
    u16* __restrict__ xn)
{
    int m = blockIdx.x;              // 0..2047  (b*1024+n)
    int b = m >> 10;
    int lane = threadIdx.x;
    const float* xr = x + (size_t)m * 512;
    int c0 = lane * 8;
    float4 v0 = *(const float4*)(xr + c0);
    float4 v1 = *(const float4*)(xr + c0 + 4);
    float xv[8] = {v0.x, v0.y, v0.z, v0.w, v1.x, v1.y, v1.z, v1.w};
    float s = 0.f, ss = 0.f;
    #pragma unroll
    for (int e = 0; e < 8; e++) { s += xv[e]; ss += xv[e]*xv[e]; }
    #pragma unroll
    for (int off = 1; off < 64; off <<= 1) {
        s  += __shfl_xor(s, off);
        ss += __shfl_xor(ss, off);
    }
    float mu = s * (1.f/512.f);
    float var = ss * (1.f/512.f) - mu*mu;
    float rs = rsqrtf(var + 1e-5f);
    float mk = seq_mask[m];
    u16x8 ov;
    #pragma unroll
    for (int e = 0; e < 8; e++) {
        int c = c0 + e;
        float sc = tbuf[b*1024 + c] + 1.f;
        float sh = tbuf[b*1024 + 512 + c];
        float val = ((xv[e] - mu) * rs * gamma[c] * sc + sh) * mk;
        ov[e] = f2b(val);
    }
    *(u16x8*)&xn[(size_t)m * 512 + c0] = ov;
}

// ---------------- kernel 3: f32 -> bf16 convert
__global__ __launch_bounds__(256) void cvt_bf16_kernel(
    const float* __restrict__ src, u16* __restrict__ dst, int n4)
{
    int i = blockIdx.x * 256 + threadIdx.x;
    if (i < n4) {
        float4 v = ((const float4*)src)[i];
        u16x8 dummy; (void)dummy;
        ushort4 o;
        o.x = f2b(v.x); o.y = f2b(v.y); o.z = f2b(v.z); o.w = f2b(v.w);
        *(ushort4*)&dst[(size_t)i * 4] = o;
    }
}

// ---------------- kernel 4: QKV projection GEMM (M=2048, K=512, N=1536)
// out columns: [0,512) -> q (scaled 0.125), [512,1024) -> k, [1024,1536) -> vT
__global__ __launch_bounds__(256) void qkv_gemm_kernel(
    const u16* __restrict__ xn, const u16* __restrict__ wqkv,
    u16* __restrict__ qb, u16* __restrict__ kb, u16* __restrict__ vT)
{
    __shared__ u16 As[64][40];
    __shared__ u16 Bs[64][40];
    const int tid = threadIdx.x;
    const int lane = tid & 63, wid = tid >> 6;
    const int wr = wid >> 1, wc = wid & 1;
    const int li = lane & 15, g = lane >> 4;
    const int m0 = blockIdx.x * 64, n0 = blockIdx.y * 64;

    f32x4 acc[2][2] = {};
    const int lrow = tid >> 2, lcol = (tid & 3) * 8;
    for (int k0 = 0; k0 < 512; k0 += 32) {
        *(bf16x8*)&As[lrow][lcol] = *(const bf16x8*)&xn[(size_t)(m0+lrow)*512 + k0 + lcol];
        *(bf16x8*)&Bs[lrow][lcol] = *(const bf16x8*)&wqkv[(size_t)(n0+lrow)*512 + k0 + lcol];
        __syncthreads();
        bf16x8 a[2], b[2];
        #pragma unroll
        for (int fi = 0; fi < 2; fi++) a[fi] = *(const bf16x8*)&As[wr*32 + fi*16 + li][g*8];
        #pragma unroll
        for (int fj = 0; fj < 2; fj++) b[fj] = *(const bf16x8*)&Bs[wc*32 + fj*16 + li][g*8];
        #pragma unroll
        for (int fi = 0; fi < 2; fi++)
            #pragma unroll
            for (int fj = 0; fj < 2; fj++)
                acc[fi][fj] = __builtin_amdgcn_mfma_f32_16x16x32_bf16(a[fi], b[fj], acc[fi][fj], 0, 0, 0);
        __syncthreads();
    }
    #pragma unroll
    for (int fi = 0; fi < 2; fi++)
        #pragma unroll
        for (int fj = 0; fj < 2; fj++)
            #pragma unroll
            for (int r = 0; r < 4; r++) {
                int ml = wr*32 + fi*16 + g*4 + r;
                int nl = wc*32 + fj*16 + li;
                int m = m0 + ml, o = n0 + nl;
                int b = m >> 10, n = m & 1023;
                float v = acc[fi][fj][r];
                if (o < 512) {
                    qb[((size_t)(b*8 + (o>>6))*1024 + n)*64 + (o&63)] = f2b(v * 0.125f);
                } else if (o < 1024) {
                    int oo = o - 512;
                    kb[((size_t)(b*8 + (oo>>6))*1024 + n)*64 + (oo&63)] = f2b(v);
                } else {
                    int oo = o - 1024;
                    vT[((size_t)(b*8 + (oo>>6))*64 + (oo&63))*1024 + n] = f2b(v);
                }
            }
}

// ---------------- kernel 5: bias[b][h][i][j] = sum_a Wb[h][a]*attn_bias[b][a][i][j] + bb[h]
__global__ __launch_bounds__(256) void bias_kernel(
    const float* __restrict__ ab, const float* __restrict__ Wb,
    const float* __restrict__ bbv, u16* __restrict__ bias)
{
    __shared__ float wbs[128];
    __shared__ float bbs[8];
    int tid = threadIdx.x;
    if (tid < 128) wbs[tid] = Wb[tid];
    if (tid < 8) bbs[tid] = bbv[tid];
    __syncthreads();
    int idx = blockIdx.x * 256 + tid;     // 524288 total
    int b = idx >> 18;
    int r = idx & 262143;
    int i = r >> 8;
    int j = (r & 255) * 4;
    float4 acc[8];
    #pragma unroll
    for (int h = 0; h < 8; h++) acc[h] = make_float4(bbs[h], bbs[h], bbs[h], bbs[h]);
    #pragma unroll
    for (int a = 0; a < 16; a++) {
        float4 v = *(const float4*)&ab[(((size_t)(b*16 + a)) << 20) + ((size_t)i << 10) + j];
        #pragma unroll
        for (int h = 0; h < 8; h++) {
            float w = wbs[h*16 + a];
            acc[h].x += w*v.x; acc[h].y += w*v.y; acc[h].z += w*v.z; acc[h].w += w*v.w;
        }
    }
    #pragma unroll
    for (int h = 0; h < 8; h++) {
        ushort4 o;
        o.x = f2b(acc[h].x); o.y = f2b(acc[h].y); o.z = f2b(acc[h].z); o.w = f2b(acc[h].w);
        *(ushort4*)&bias[(((size_t)(b*8 + h)) << 20) + ((size_t)i << 10) + j] = o;
    }
}

// ---------------- kernel 6: flash attention, 64 q-rows per block, 4 waves
__global__ __launch_bounds__(256) void attn_kernel(
    const u16* __restrict__ qb, const u16* __restrict__ kb, const u16* __restrict__ vT,
    const u16* __restrict__ bias, const float* __restrict__ seq_mask,
    u16* __restrict__ attn_out)
{
    __shared__ u16 Qs[64][72];
    __shared__ u16 Ks[64][72];
    __shared__ u16 Vs[64][72];   // V^T tile: [d][j]
    __shared__ u16 Ps[4][16][72];
    int tid = threadIdx.x;
    int lane = tid & 63, w = tid >> 6;
    int li = lane & 15, g = lane >> 4;
    int it = blockIdx.x, h = blockIdx.y, b = blockIdx.z;
    int i0 = it * 64;
    const u16* qp = qb + ((size_t)(b*8 + h)*1024 + i0) * 64;
    const u16* kp = kb + (size_t)(b*8 + h)*1024*64;
    const u16* vp = vT + (size_t)(b*8 + h)*64*1024;
    const u16* bp = bias + (((size_t)(b*8 + h)) << 20);

    for (int e = tid; e < 512; e += 256) {
        int row = e >> 3, c = (e & 7) * 8;
        *(bf16x8*)&Qs[row][c] = *(const bf16x8*)&qp[(size_t)row*64 + c];
    }

    f32x4 oacc[4] = {};
    float m_run[4], l_run[4];
    #pragma unroll
    for (int r = 0; r < 4; r++) { m_run[r] = -3e38f; l_run[r] = 0.f; }
    float mi[4];
    #pragma unroll
    for (int r = 0; r < 4; r++) mi[r] = seq_mask[b*1024 + i0 + w*16 + g*4 + r];

    for (int jt = 0; jt < 16; jt++) {
        __syncthreads();
        for (int e = tid; e < 512; e += 256) {
            int row = e >> 3, c = (e & 7) * 8;
            *(bf16x8*)&Ks[row][c] = *(const bf16x8*)&kp[(size_t)(jt*64 + row)*64 + c];
            *(bf16x8*)&Vs[row][c] = *(const bf16x8*)&vp[(size_t)row*1024 + jt*64 + c];
        }
        __syncthreads();
        // S = Q K^T  (rows w*16..w*16+16 x 64 j)
        f32x4 s[4] = {};
        bf16x8 aq0 = *(const bf16x8*)&Qs[w*16 + li][g*8];
        bf16x8 aq1 = *(const bf16x8*)&Qs[w*16 + li][32 + g*8];
        #pragma unroll
        for (int fj = 0; fj < 4; fj++) {
            bf16x8 bk0 = *(const bf16x8*)&Ks[fj*16 + li][g*8];
            bf16x8 bk1 = *(const bf16x8*)&Ks[fj*16 + li][32 + g*8];
            s[fj] = __builtin_amdgcn_mfma_f32_16x16x32_bf16(aq0, bk0, s[fj], 0, 0, 0);
            s[fj] = __builtin_amdgcn_mfma_f32_16x16x32_bf16(aq1, bk1, s[fj], 0, 0, 0);
        }
        // bias + mask
        float pmax[4] = {-3e38f, -3e38f, -3e38f, -3e38f};
        #pragma unroll
        for (int fj = 0; fj < 4; fj++) {
            int j = jt*64 + fj*16 + li;
            float mj = seq_mask[b*1024 + j];
            #pragma unroll
            for (int r = 0; r < 4; r++) {
                int i = i0 + w*16 + g*4 + r;
                float sv = s[fj][r] + b2f(bp[((size_t)i << 10) + j]);
                sv -= (1.f - mi[r]*mj) * 1e6f;
                s[fj][r] = sv;
                pmax[r] = fmaxf(pmax[r], sv);
            }
        }
        #pragma unroll
        for (int r = 0; r < 4; r++)
            #pragma unroll
            for (int off = 1; off < 16; off <<= 1)
                pmax[r] = fmaxf(pmax[r], __shfl_xor(pmax[r], off));
        float alpha[4], psum[4] = {0.f, 0.f, 0.f, 0.f}, mnew[4];
        #pragma unroll
        for (int r = 0; r < 4; r++) {
            mnew[r] = fmaxf(m_run[r], pmax[r]);
            alpha[r] = __expf(m_run[r] - mnew[r]);
            m_run[r] = mnew[r];
        }
        #pragma unroll
        for (int fj = 0; fj < 4; fj++)
            #pragma unroll
            for (int r = 0; r < 4; r++) {
                float p = __expf(s[fj][r] - mnew[r]);
                s[fj][r] = p;
                psum[r] += p;
            }
        #pragma unroll
        for (int r = 0; r < 4; r++) {
            #pragma unroll
            for (int off = 1; off < 16; off <<= 1) psum[r] += __shfl_xor(psum[r], off);
            l_run[r] = l_run[r]*alpha[r] + psum[r];
        }
        // write P (wave-private region)
        #pragma unroll
        for (int fj = 0; fj < 4; fj++)
            #pragma unroll
            for (int r = 0; r < 4; r++)
                Ps[w][g*4 + r][fj*16 + li] = f2b(s[fj][r]);
        #pragma unroll
        for (int fd = 0; fd < 4; fd++)
            #pragma unroll
            for (int r = 0; r < 4; r++)
                oacc[fd][r] *= alpha[r];
        // O += P V
        bf16x8 ap0 = *(const bf16x8*)&Ps[w][li][g*8];
        bf16x8 ap1 = *(const bf16x8*)&Ps[w][li][32 + g*8];
        #pragma unroll
        for (int fd = 0; fd < 4; fd++) {
            bf16x8 bv0 = *(const bf16x8*)&Vs[fd*16 + li][g*8];
            bf16x8 bv1 = *(const bf16x8*)&Vs[fd*16 + li][32 + g*8];
            oacc[fd] = __builtin_amdgcn_mfma_f32_16x16x32_bf16(ap0, bv0, oacc[fd], 0, 0, 0);
            oacc[fd] = __builtin_amdgcn_mfma_f32_16x16x32_bf16(ap1, bv1, oacc[fd], 0, 0, 0);
        }
    }
    #pragma unroll
    for (int fd = 0; fd < 4; fd++)
        #pragma unroll
        for (int r = 0; r < 4; r++) {
            int i = i0 + w*16 + g*4 + r;
            int col = h*64 + fd*16 + li;
            float val = oacc[fd][r] / l_run[r];
            attn_out[((size_t)(b*1024 + i))*512 + col] = f2b(val);
        }
}

// ---------------- kernel 7: out = attn_out @ Wo^T  (M=2048,K=512,N=512), * mask, f32
__global__ __launch_bounds__(256) void out_gemm_kernel(
    const u16* __restrict__ aout, const u16* __restrict__ wo,
    const float* __restrict__ seq_mask, float* __restrict__ out)
{
    __shared__ u16 As[64][40];
    __shared__ u16 Bs[64][40];
    const int tid = threadIdx.x;
    const int lane = tid & 63, wid = tid >> 6;
    const int wr = wid >> 1, wc = wid & 1;
    const int li = lane & 15, g = lane >> 4;
    const int m0 = blockIdx.x * 64, n0 = blockIdx.y * 64;

    f32x4 acc[2][2] = {};
    const int lrow = tid >> 2, lcol = (tid & 3) * 8;
    for (int k0 = 0; k0 < 512; k0 += 32) {
        *(bf16x8*)&As[lrow][lcol] = *(const bf16x8*)&aout[(size_t)(m0+lrow)*512 + k0 + lcol];
        *(bf16x8*)&Bs[lrow][lcol] = *(const bf16x8*)&wo[(size_t)(n0+lrow)*512 + k0 + lcol];
        __syncthreads();
        bf16x8 a[2], b[2];
        #pragma unroll
        for (int fi = 0; fi < 2; fi++) a[fi] = *(const bf16x8*)&As[wr*32 + fi*16 + li][g*8];
        #pragma unroll
        for (int fj = 0; fj < 2; fj++) b[fj] = *(const bf16x8*)&Bs[wc*32 + fj*16 + li][g*8];
        #pragma unroll
        for (int fi = 0; fi < 2; fi++)
            #pragma unroll
            for (int fj = 0; fj < 2; fj++)
                acc[fi][fj] = __builtin_amdgcn_mfma_f32_16x16x32_bf16(a[fi], b[fj], acc[fi][fj], 0, 0, 0);
        __syncthreads();
    }
    #pragma unroll
    for (int fi = 0; fi < 2; fi++)
        #pragma unroll
        for (int fj = 0; fj < 2; fj++)
            #pragma unroll
            for (int r = 0; r < 4; r++) {
                int m = m0 + wr*32 + fi*16 + g*4 + r;
                int o = n0 + wc*32 + fj*16 + li;
                out[(size_t)m*512 + o] = acc[fi][fj][r] * seq_mask[m];
            }
}

extern "C" void kernel_launch(void* const* d_in, const int* in_sizes, int n_in,
                              void* d_out, int out_size, void* d_ws, size_t ws_size,
                              hipStream_t stream) {
    const float* x         = (const float*)d_in[0];
    // d_in[1] residx: unused by reference
    const float* timep     = (const float*)d_in[2];
    const float* attn_bias = (const float*)d_in[3];
    const float* seq_mask  = (const float*)d_in[4];
    const float* gamma     = (const float*)d_in[5];
    const float* Wt        = (const float*)d_in[6];
    const float* bt        = (const float*)d_in[7];
    const float* Wb        = (const float*)d_in[8];
    const float* bb        = (const float*)d_in[9];
    const float* Wq        = (const float*)d_in[10];
    const float* Wkv       = (const float*)d_in[11];
    const float* Wo        = (const float*)d_in[12];
    float* out = (float*)d_out;

    char* ws = (char*)d_ws;
    size_t off = 0;
    auto alloc = [&](size_t bytes) { char* p = ws + off; off += (bytes + 255) & ~(size_t)255; return p; };
    float* tbuf  = (float*)alloc(2 * 1024 * 4);
    u16* xn      = (u16*)alloc((size_t)2048 * 512 * 2);
    u16* wqkv    = (u16*)alloc((size_t)1536 * 512 * 2);
    u16* wo      = (u16*)alloc((size_t)512 * 512 * 2);
    u16* qb      = (u16*)alloc((size_t)2 * 8 * 1024 * 64 * 2);
    u16* kb      = (u16*)alloc((size_t)2 * 8 * 1024 * 64 * 2);
    u16* vT      = (u16*)alloc((size_t)2 * 8 * 64 * 1024 * 2);
    u16* bias    = (u16*)alloc((size_t)2 * 8 * 1024 * 1024 * 2);
    u16* aout    = (u16*)alloc((size_t)2048 * 512 * 2);
    (void)ws_size;

    // weight converts
    cvt_bf16_kernel<<<(512*512/4 + 255)/256, 256, 0, stream>>>(Wq, wqkv, 512*512/4);
    cvt_bf16_kernel<<<(1024*512/4 + 255)/256, 256, 0, stream>>>(Wkv, wqkv + 512*512, 1024*512/4);
    cvt_bf16_kernel<<<(512*512/4 + 255)/256, 256, 0, stream>>>(Wo, wo, 512*512/4);

    time_cond_kernel<<<16, 128, 0, stream>>>(timep, Wt, bt, tbuf);
    ln_cond_kernel<<<2048, 64, 0, stream>>>(x, gamma, tbuf, seq_mask, xn);
    qkv_gemm_kernel<<<dim3(32, 24), 256, 0, stream>>>(xn, wqkv, qb, kb, vT);
    bias_kernel<<<2048, 256, 0, stream>>>(attn_bias, Wb, bb, bias);
    attn_kernel<<<dim3(16, 8, 2), 256, 0, stream>>>(qb, kb, vT, bias, seq_mask, aout);
    out_gemm_kernel<<<dim3(32, 8), 256, 0, stream>>>(aout, wo, seq_mask, out);
}

// Round 3
// 104.553 us; speedup vs baseline: 1.1270x; 1.1270x over previous
//
#include <hip/hip_runtime.h>
#include <cstdint>
#include <cstddef>

typedef __bf16 bf16x8 __attribute__((ext_vector_type(8)));
typedef float f32x4 __attribute__((ext_vector_type(4)));
typedef unsigned short u16;
typedef unsigned short u16x8 __attribute__((ext_vector_type(8)));

__device__ __forceinline__ u16 f2b(float f) {
    union { float f; uint32_t u; } v; v.f = f;
    uint32_t r = v.u + 0x7fffu + ((v.u >> 16) & 1u);
    return (u16)(r >> 16);
}
__device__ __forceinline__ float b2f(u16 h) {
    union { uint32_t u; float f; } v; v.u = ((uint32_t)h) << 16; return v.f;
}

// ---------------- kernel 1: prep = weight bf16 converts + time conditioning
// blocks 0..1023: convert Wq/Wkv/Wo (262144 float4s total)
// blocks 1024..1031: t = silu(time) @ Wt^T + bt -> tbuf[B][1024]
__global__ __launch_bounds__(256) void prep_kernel(
    const float* __restrict__ Wq, const float* __restrict__ Wkv, const float* __restrict__ Wo,
    const float* __restrict__ timep, const float* __restrict__ Wt, const float* __restrict__ bt,
    u16* __restrict__ wqkv, u16* __restrict__ wo, float* __restrict__ tbuf)
{
    __shared__ float st[512];
    int bx = blockIdx.x, tid = threadIdx.x;
    if (bx < 1024) {
        int i = bx * 256 + tid;
        float4 v; u16* dp;
        if (i < 65536)      { v = ((const float4*)Wq)[i];            dp = wqkv + (size_t)i * 4; }
        else if (i < 196608){ int k = i - 65536;  v = ((const float4*)Wkv)[k]; dp = wqkv + 262144 + (size_t)k * 4; }
        else                { int k = i - 196608; v = ((const float4*)Wo)[k];  dp = wo + (size_t)k * 4; }
        ushort4 o;
        o.x = f2b(v.x); o.y = f2b(v.y); o.z = f2b(v.z); o.w = f2b(v.w);
        *(ushort4*)dp = o;
    } else {
        int bx2 = bx - 1024;          // 8 blocks
        int b = bx2 >> 2, ch = bx2 & 3;
        for (int k = tid; k < 512; k += 256) {
            float v = timep[b * 512 + k];
            st[k] = v / (1.f + __expf(-v));
        }
        __syncthreads();
        int o = ch * 256 + tid;
        const float4* wrow = (const float4*)(Wt + (size_t)o * 512);
        float acc = bt[o];
        #pragma unroll 4
        for (int k4 = 0; k4 < 128; k4++) {
            float4 w = wrow[k4];
            acc += st[k4*4+0]*w.x + st[k4*4+1]*w.y + st[k4*4+2]*w.z + st[k4*4+3]*w.w;
        }
        tbuf[b * 1024 + o] = acc;
    }
}

// ---------------- kernel 2: LayerNorm + (scale+1)*x + shift, * mask -> xn bf16
__global__ __launch_bounds__(64) void ln_cond_kernel(
    const float* __restrict__ x, const float* __restrict__ gamma,
    const float* __restrict__ tbuf, const float* __restrict__ seq_mask,
    u16* __restrict__ xn)
{
    int m = blockIdx.x;              // 0..2047  (b*1024+n)
    int b = m >> 10;
    int lane = threadIdx.x;
    const float* xr = x + (size_t)m * 512;
    int c0 = lane * 8;
    float4 v0 = *(const float4*)(xr + c0);
    float4 v1 = *(const float4*)(xr + c0 + 4);
    float xv[8] = {v0.x, v0.y, v0.z, v0.w, v1.x, v1.y, v1.z, v1.w};
    float s = 0.f, ss = 0.f;
    #pragma unroll
    for (int e = 0; e < 8; e++) { s += xv[e]; ss += xv[e]*xv[e]; }
    #pragma unroll
    for (int off = 1; off < 64; off <<= 1) {
        s  += __shfl_xor(s, off);
        ss += __shfl_xor(ss, off);
    }
    float mu = s * (1.f/512.f);
    float var = ss * (1.f/512.f) - mu*mu;
    float rs = rsqrtf(var + 1e-5f);
    float mk = seq_mask[m];
    u16x8 ov;
    #pragma unroll
    for (int e = 0; e < 8; e++) {
        int c = c0 + e;
        float sc = tbuf[b*1024 + c] + 1.f;
        float sh = tbuf[b*1024 + 512 + c];
        float val = ((xv[e] - mu) * rs * gamma[c] * sc + sh) * mk;
        ov[e] = f2b(val);
    }
    *(u16x8*)&xn[(size_t)m * 512 + c0] = ov;
}

// ---------------- kernel 3: QKV projection GEMM (M=2048, K=512, N=1536)
// out columns: [0,512) -> q (scaled 0.125), [512,1024) -> k, [1024,1536) -> vT
__global__ __launch_bounds__(256) void qkv_gemm_kernel(
    const u16* __restrict__ xn, const u16* __restrict__ wqkv,
    u16* __restrict__ qb, u16* __restrict__ kb, u16* __restrict__ vT)
{
    __shared__ u16 As[64][40];
    __shared__ u16 Bs[64][40];
    const int tid = threadIdx.x;
    const int lane = tid & 63, wid = tid >> 6;
    const int wr = wid >> 1, wc = wid & 1;
    const int li = lane & 15, g = lane >> 4;
    const int m0 = blockIdx.x * 64, n0 = blockIdx.y * 64;

    f32x4 acc[2][2] = {};
    const int lrow = tid >> 2, lcol = (tid & 3) * 8;
    for (int k0 = 0; k0 < 512; k0 += 32) {
        *(bf16x8*)&As[lrow][lcol] = *(const bf16x8*)&xn[(size_t)(m0+lrow)*512 + k0 + lcol];
        *(bf16x8*)&Bs[lrow][lcol] = *(const bf16x8*)&wqkv[(size_t)(n0+lrow)*512 + k0 + lcol];
        __syncthreads();
        bf16x8 a[2], b[2];
        #pragma unroll
        for (int fi = 0; fi < 2; fi++) a[fi] = *(const bf16x8*)&As[wr*32 + fi*16 + li][g*8];
        #pragma unroll
        for (int fj = 0; fj < 2; fj++) b[fj] = *(const bf16x8*)&Bs[wc*32 + fj*16 + li][g*8];
        #pragma unroll
        for (int fi = 0; fi < 2; fi++)
            #pragma unroll
            for (int fj = 0; fj < 2; fj++)
                acc[fi][fj] = __builtin_amdgcn_mfma_f32_16x16x32_bf16(a[fi], b[fj], acc[fi][fj], 0, 0, 0);
        __syncthreads();
    }
    #pragma unroll
    for (int fi = 0; fi < 2; fi++)
        #pragma unroll
        for (int fj = 0; fj < 2; fj++) {
            int nl = wc*32 + fj*16 + li;
            int o = n0 + nl;
            int m_base = m0 + wr*32 + fi*16 + g*4;
            if (o < 1024) {
                #pragma unroll
                for (int r = 0; r < 4; r++) {
                    int m = m_base + r;
                    int b = m >> 10, n = m & 1023;
                    float v = acc[fi][fj][r];
                    if (o < 512) {
                        qb[((size_t)(b*8 + (o>>6))*1024 + n)*64 + (o&63)] = f2b(v * 0.125f);
                    } else {
                        int oo = o - 512;
                        kb[((size_t)(b*8 + (oo>>6))*1024 + n)*64 + (oo&63)] = f2b(v);
                    }
                }
            } else {
                // V^T: 4 consecutive n at fixed d -> one ushort4 store
                int oo = o - 1024;
                int b = m_base >> 10, n = m_base & 1023;
                ushort4 ov;
                ov.x = f2b(acc[fi][fj][0]); ov.y = f2b(acc[fi][fj][1]);
                ov.z = f2b(acc[fi][fj][2]); ov.w = f2b(acc[fi][fj][3]);
                *(ushort4*)&vT[((size_t)(b*8 + (oo>>6))*64 + (oo&63))*1024 + n] = ov;
            }
        }
}

// ---------------- kernel 4: bias_t[bh][it][jt][64][64] = sum_a Wb[h][a]*ab[b][a][i][j] + bb[h]
__global__ __launch_bounds__(256) void bias_kernel(
    const float* __restrict__ ab, const float* __restrict__ Wb,
    const float* __restrict__ bbv, u16* __restrict__ bias_t)
{
    __shared__ float wbs[128];
    __shared__ float bbs[8];
    int tid = threadIdx.x;
    if (tid < 128) wbs[tid] = Wb[tid];
    if (tid < 8) bbs[tid] = bbv[tid];
    __syncthreads();
    int idx = blockIdx.x * 256 + tid;     // 524288 total
    int b = idx >> 18;
    int r = idx & 262143;
    int i = r >> 8;
    int j = (r & 255) * 4;
    f32x4 acc[8];
    #pragma unroll
    for (int h = 0; h < 8; h++) { acc[h][0] = bbs[h]; acc[h][1] = bbs[h]; acc[h][2] = bbs[h]; acc[h][3] = bbs[h]; }
    #pragma unroll
    for (int a = 0; a < 16; a++) {
        const f32x4* src = (const f32x4*)&ab[(((size_t)(b*16 + a)) << 20) + ((size_t)i << 10) + j];
        f32x4 v = __builtin_nontemporal_load(src);
        #pragma unroll
        for (int h = 0; h < 8; h++) {
            float w = wbs[h*16 + a];
            acc[h][0] += w*v[0]; acc[h][1] += w*v[1]; acc[h][2] += w*v[2]; acc[h][3] += w*v[3];
        }
    }
    int it = i >> 6, il = i & 63, jt = j >> 6, jl = j & 63;
    #pragma unroll
    for (int h = 0; h < 8; h++) {
        ushort4 o;
        o.x = f2b(acc[h][0]); o.y = f2b(acc[h][1]); o.z = f2b(acc[h][2]); o.w = f2b(acc[h][3]);
        size_t off = ((((size_t)(b*8 + h)*16 + it)*16 + jt) << 12) + il*64 + jl;
        *(ushort4*)&bias_t[off] = o;
    }
}

// ---------------- kernel 5: flash attention, 64 q-rows per block, 4 waves
// double-buffered K/V/bias LDS, async-stage split (load regs early, ds_write late)
__global__ __launch_bounds__(256) void attn_kernel(
    const u16* __restrict__ qb, const u16* __restrict__ kb, const u16* __restrict__ vT,
    const u16* __restrict__ bias_t, const float* __restrict__ seq_mask,
    u16* __restrict__ attn_out)
{
    __shared__ u16 Qs[64][72];
    __shared__ u16 Ks[2][64][72];
    __shared__ u16 Vs[2][64][72];   // V^T tile: [d][j]
    __shared__ u16 Bs[2][64][72];   // bias tile: [i_local][j_local]
    __shared__ u16 Ps[4][16][72];
    __shared__ float mjs[1024];
    int tid = threadIdx.x;
    int lane = tid & 63, w = tid >> 6;
    int li = lane & 15, g = lane >> 4;
    int it = blockIdx.x, h = blockIdx.y, b = blockIdx.z;
    int i0 = it * 64;
    const u16* qp = qb + ((size_t)(b*8 + h)*1024 + i0) * 64;
    const u16* kp = kb + (size_t)(b*8 + h)*1024*64;
    const u16* vp = vT + (size_t)(b*8 + h)*64*1024;
    const u16* bp = bias_t + ((((size_t)(b*8 + h))*16 + it) << 16);   // + jt*4096

    // stage Q (contiguous 8 KB) and mask row
    *(bf16x8*)&Qs[tid>>2][(tid&3)*16]     = *(const bf16x8*)&qp[tid*16];
    *(bf16x8*)&Qs[tid>>2][(tid&3)*16 + 8] = *(const bf16x8*)&qp[tid*16 + 8];
    ((float4*)mjs)[tid] = ((const float4*)(seq_mask + b*1024))[tid];

    const int krow = tid >> 2, kcol = (tid & 3) * 16;
    const int vrow = tid >> 3, vcol = (tid & 7) * 8;

    bf16x8 kr0, kr1, vr0, vr1, br0, br1;
    #define LOADT(jt_) do { \
        kr0 = *(const bf16x8*)&kp[(size_t)(jt_)*4096 + tid*16]; \
        kr1 = *(const bf16x8*)&kp[(size_t)(jt_)*4096 + tid*16 + 8]; \
        br0 = *(const bf16x8*)&bp[(size_t)(jt_)*4096 + tid*16]; \
        br1 = *(const bf16x8*)&bp[(size_t)(jt_)*4096 + tid*16 + 8]; \
        vr0 = *(const bf16x8*)&vp[(size_t)vrow*1024 + (jt_)*64 + vcol]; \
        vr1 = *(const bf16x8*)&vp[(size_t)(vrow+32)*1024 + (jt_)*64 + vcol]; \
    } while (0)
    #define STORET(buf_) do { \
        *(bf16x8*)&Ks[buf_][krow][kcol]     = kr0; \
        *(bf16x8*)&Ks[buf_][krow][kcol + 8] = kr1; \
        *(bf16x8*)&Bs[buf_][krow][kcol]     = br0; \
        *(bf16x8*)&Bs[buf_][krow][kcol + 8] = br1; \
        *(bf16x8*)&Vs[buf_][vrow][vcol]      = vr0; \
        *(bf16x8*)&Vs[buf_][vrow + 32][vcol] = vr1; \
    } while (0)

    f32x4 oacc[4] = {};
    float m_run[4], l_run[4];
    #pragma unroll
    for (int r = 0; r < 4; r++) { m_run[r] = -3e38f; l_run[r] = 0.f; }
    float mi[4];
    #pragma unroll
    for (int r = 0; r < 4; r++) mi[r] = seq_mask[b*1024 + i0 + w*16 + g*4 + r];

    LOADT(0); STORET(0);
    __syncthreads();

    for (int jt = 0; jt < 16; jt++) {
        int cur = jt & 1;
        if (jt < 15) LOADT(jt + 1);
        // S = Q K^T  (rows w*16..+15 x 64 j)
        f32x4 s[4] = {};
        bf16x8 aq0 = *(const bf16x8*)&Qs[w*16 + li][g*8];
        bf16x8 aq1 = *(const bf16x8*)&Qs[w*16 + li][32 + g*8];
        #pragma unroll
        for (int fj = 0; fj < 4; fj++) {
            bf16x8 bk0 = *(const bf16x8*)&Ks[cur][fj*16 + li][g*8];
            bf16x8 bk1 = *(const bf16x8*)&Ks[cur][fj*16 + li][32 + g*8];
            s[fj] = __builtin_amdgcn_mfma_f32_16x16x32_bf16(aq0, bk0, s[fj], 0, 0, 0);
            s[fj] = __builtin_amdgcn_mfma_f32_16x16x32_bf16(aq1, bk1, s[fj], 0, 0, 0);
        }
        // bias (LDS) + mask
        float pmax[4] = {-3e38f, -3e38f, -3e38f, -3e38f};
        #pragma unroll
        for (int fj = 0; fj < 4; fj++) {
            float mj = mjs[jt*64 + fj*16 + li];
            #pragma unroll
            for (int r = 0; r < 4; r++) {
                float sv = s[fj][r] + b2f(Bs[cur][w*16 + g*4 + r][fj*16 + li]);
                sv -= (1.f - mi[r]*mj) * 1e6f;
                s[fj][r] = sv;
                pmax[r] = fmaxf(pmax[r], sv);
            }
        }
        #pragma unroll
        for (int r = 0; r < 4; r++)
            #pragma unroll
            for (int off = 1; off < 16; off <<= 1)
                pmax[r] = fmaxf(pmax[r], __shfl_xor(pmax[r], off));
        float alpha[4], psum[4] = {0.f, 0.f, 0.f, 0.f}, mnew[4];
        #pragma unroll
        for (int r = 0; r < 4; r++) {
            mnew[r] = fmaxf(m_run[r], pmax[r]);
            alpha[r] = __expf(m_run[r] - mnew[r]);
            m_run[r] = mnew[r];
        }
        #pragma unroll
        for (int fj = 0; fj < 4; fj++)
            #pragma unroll
            for (int r = 0; r < 4; r++) {
                float p = __expf(s[fj][r] - mnew[r]);
                s[fj][r] = p;
                psum[r] += p;
            }
        #pragma unroll
        for (int r = 0; r < 4; r++) {
            #pragma unroll
            for (int off = 1; off < 16; off <<= 1) psum[r] += __shfl_xor(psum[r], off);
            l_run[r] = l_run[r]*alpha[r] + psum[r];
        }
        // write P (wave-private region)
        #pragma unroll
        for (int fj = 0; fj < 4; fj++)
            #pragma unroll
            for (int r = 0; r < 4; r++)
                Ps[w][g*4 + r][fj*16 + li] = f2b(s[fj][r]);
        #pragma unroll
        for (int fd = 0; fd < 4; fd++)
            #pragma unroll
            for (int r = 0; r < 4; r++)
                oacc[fd][r] *= alpha[r];
        // O += P V
        bf16x8 ap0 = *(const bf16x8*)&Ps[w][li][g*8];
        bf16x8 ap1 = *(const bf16x8*)&Ps[w][li][32 + g*8];
        #pragma unroll
        for (int fd = 0; fd < 4; fd++) {
            bf16x8 bv0 = *(const bf16x8*)&Vs[cur][fd*16 + li][g*8];
            bf16x8 bv1 = *(const bf16x8*)&Vs[cur][fd*16 + li][32 + g*8];
            oacc[fd] = __builtin_amdgcn_mfma_f32_16x16x32_bf16(ap0, bv0, oacc[fd], 0, 0, 0);
            oacc[fd] = __builtin_amdgcn_mfma_f32_16x16x32_bf16(ap1, bv1, oacc[fd], 0, 0, 0);
        }
        if (jt < 15) STORET(cur ^ 1);
        __syncthreads();
    }
    #pragma unroll
    for (int fd = 0; fd < 4; fd++)
        #pragma unroll
        for (int r = 0; r < 4; r++) {
            int i = i0 + w*16 + g*4 + r;
            int col = h*64 + fd*16 + li;
            float val = oacc[fd][r] / l_run[r];
            attn_out[((size_t)(b*1024 + i))*512 + col] = f2b(val);
        }
    #undef LOADT
    #undef STORET
}

// ---------------- kernel 6: out = attn_out @ Wo^T  (M=2048,K=512,N=512), * mask, f32
__global__ __launch_bounds__(256) void out_gemm_kernel(
    const u16* __restrict__ aout, const u16* __restrict__ wo,
    const float* __restrict__ seq_mask, float* __restrict__ out)
{
    __shared__ u16 As[64][40];
    __shared__ u16 Bs[64][40];
    const int tid = threadIdx.x;
    const int lane = tid & 63, wid = tid >> 6;
    const int wr = wid >> 1, wc = wid & 1;
    const int li = lane & 15, g = lane >> 4;
    const int m0 = blockIdx.x * 64, n0 = blockIdx.y * 64;

    f32x4 acc[2][2] = {};
    const int lrow = tid >> 2, lcol = (tid & 3) * 8;
    for (int k0 = 0; k0 < 512; k0 += 32) {
        *(bf16x8*)&As[lrow][lcol] = *(const bf16x8*)&aout[(size_t)(m0+lrow)*512 + k0 + lcol];
        *(bf16x8*)&Bs[lrow][lcol] = *(const bf16x8*)&wo[(size_t)(n0+lrow)*512 + k0 + lcol];
        __syncthreads();
        bf16x8 a[2], b[2];
        #pragma unroll
        for (int fi = 0; fi < 2; fi++) a[fi] = *(const bf16x8*)&As[wr*32 + fi*16 + li][g*8];
        #pragma unroll
        for (int fj = 0; fj < 2; fj++) b[fj] = *(const bf16x8*)&Bs[wc*32 + fj*16 + li][g*8];
        #pragma unroll
        for (int fi = 0; fi < 2; fi++)
            #pragma unroll
            for (int fj = 0; fj < 2; fj++)
                acc[fi][fj] = __builtin_amdgcn_mfma_f32_16x16x32_bf16(a[fi], b[fj], acc[fi][fj], 0, 0, 0);
        __syncthreads();
    }
    #pragma unroll
    for (int fi = 0; fi < 2; fi++)
        #pragma unroll
        for (int fj = 0; fj < 2; fj++)
            #pragma unroll
            for (int r = 0; r < 4; r++) {
                int m = m0 + wr*32 + fi*16 + g*4 + r;
                int o = n0 + wc*32 + fj*16 + li;
                out[(size_t)m*512 + o] = acc[fi][fj][r] * seq_mask[m];
            }
}

extern "C" void kernel_launch(void* const* d_in, const int* in_sizes, int n_in,
                              void* d_out, int out_size, void* d_ws, size_t ws_size,
                              hipStream_t stream) {
    const float* x         = (const float*)d_in[0];
    // d_in[1] residx: unused by reference
    const float* timep     = (const float*)d_in[2];
    const float* attn_bias = (const float*)d_in[3];
    const float* seq_mask  = (const float*)d_in[4];
    const float* gamma     = (const float*)d_in[5];
    const float* Wt        = (const float*)d_in[6];
    const float* bt        = (const float*)d_in[7];
    const float* Wb        = (const float*)d_in[8];
    const float* bb        = (const float*)d_in[9];
    const float* Wq        = (const float*)d_in[10];
    const float* Wkv       = (const float*)d_in[11];
    const float* Wo        = (const float*)d_in[12];
    float* out = (float*)d_out;

    char* ws = (char*)d_ws;
    size_t off = 0;
    auto alloc = [&](size_t bytes) { char* p = ws + off; off += (bytes + 255) & ~(size_t)255; return p; };
    float* tbuf  = (float*)alloc(2 * 1024 * 4);
    u16* xn      = (u16*)alloc((size_t)2048 * 512 * 2);
    u16* wqkv    = (u16*)alloc((size_t)1536 * 512 * 2);
    u16* wo      = (u16*)alloc((size_t)512 * 512 * 2);
    u16* qb      = (u16*)alloc((size_t)2 * 8 * 1024 * 64 * 2);
    u16* kb      = (u16*)alloc((size_t)2 * 8 * 1024 * 64 * 2);
    u16* vT      = (u16*)alloc((size_t)2 * 8 * 64 * 1024 * 2);
    u16* bias_t  = (u16*)alloc((size_t)2 * 8 * 1024 * 1024 * 2);
    u16* aout    = (u16*)alloc((size_t)2048 * 512 * 2);
    (void)ws_size;

    prep_kernel<<<1032, 256, 0, stream>>>(Wq, Wkv, Wo, timep, Wt, bt, wqkv, wo, tbuf);
    ln_cond_kernel<<<2048, 64, 0, stream>>>(x, gamma, tbuf, seq_mask, xn);
    qkv_gemm_kernel<<<dim3(32, 24), 256, 0, stream>>>(xn, wqkv, qb, kb, vT);
    bias_kernel<<<2048, 256, 0, stream>>>(attn_bias, Wb, bb, bias_t);
    attn_kernel<<<dim3(16, 8, 2), 256, 0, stream>>>(qb, kb, vT, bias_t, seq_mask, aout);
    out_gemm_kernel<<<dim3(32, 8), 256, 0, stream>>>(aout, wo, seq_mask, out);
}